// Round 1
// baseline (380.997 us; speedup 1.0000x reference)
//
#include <hip/hip_runtime.h>

#define N_ANCH 100800
#define BATCH 64
#define KTOP 512
#define CNT_STRIDE 64   // pad counters to 256 B so each lives on its own L2 line

// ---------------------------------------------------------------------------
// K0: zero the per-image candidate counters (ws is poisoned 0xAA each call)
// ---------------------------------------------------------------------------
__global__ void zero_cnt_kernel(int* __restrict__ cnt) {
    if (threadIdx.x < BATCH) cnt[threadIdx.x * CNT_STRIDE] = 0;
}

// ---------------------------------------------------------------------------
// K1: filter — score = p4*p5 > 0.7, compact (score_bits<<32 | ~idx) keys into
// per-image candidate lists. LDS-staged float4 loads for full coalescing.
// ONE global atomic per block (LDS-aggregated) onto a 256B-padded counter.
// grid = (ceil(N/256), B), block = 256.  (unchanged — memory-bound floor)
// ---------------------------------------------------------------------------
__global__ void filter_kernel(const float* __restrict__ pred,
                              unsigned long long* __restrict__ cand,
                              int* __restrict__ cnt, int cap) {
    __shared__ float tile[256 * 9];
    __shared__ int s_wbase[4];
    __shared__ int s_blkcnt;
    __shared__ int s_gbase;

    const int b  = blockIdx.y;
    const int r0 = blockIdx.x * 256;
    const int rows = min(256, N_ANCH - r0);
    const size_t base = ((size_t)b * N_ANCH + r0) * 9;   // divisible by 4 -> 16B aligned

    if (threadIdx.x == 0) s_blkcnt = 0;

    const int nf4 = (rows * 9) >> 2;                     // rows*9 divisible by 4 here
    const float4* __restrict__ src = (const float4*)(pred + base);
    float4* dst4 = (float4*)tile;
    for (int f = threadIdx.x; f < nf4; f += 256) dst4[f] = src[f];
    __syncthreads();

    const int t = threadIdx.x;
    const int wid = t >> 6, lane = t & 63;
    bool has = false;
    unsigned long long key = 0;
    if (t < rows) {
        float s = tile[t * 9 + 4] * tile[t * 9 + 5];
        if (s > 0.7f) {
            has = true;
            unsigned int sb = __float_as_uint(s);
            unsigned int gi = (unsigned int)(r0 + t);
            key = ((unsigned long long)sb << 32) | (unsigned long long)(~gi);
        }
    }

    unsigned long long m = __ballot(has);               // all threads reach here
    if (lane == 0) s_wbase[wid] = atomicAdd(&s_blkcnt, __popcll(m));
    __syncthreads();
    if (t == 0) s_gbase = atomicAdd(&cnt[b * CNT_STRIDE], s_blkcnt);
    __syncthreads();

    if (has) {
        int rank = __popcll(m & ((1ull << lane) - 1ull));
        int pos = s_gbase + s_wbase[wid] + rank;
        if (pos < cap) cand[(size_t)b * cap + pos] = key;
    }
}

// ---------------------------------------------------------------------------
// K2a: per-image top-512 select (histogram + suffix scan + compact + bitonic)
// then gather boxes/scores/angles to ws. grid = B, block = 512 (exactly the
// comparator count of the 1024-wide bitonic network -> no idle barrier waves).
// Writes v (valid count) to cnt[b*CNT_STRIDE + 1].
// ---------------------------------------------------------------------------
__global__ void __launch_bounds__(512)
select_kernel(const float* __restrict__ pred,
              const unsigned long long* __restrict__ cand,
              int* __restrict__ cnt,
              float4* __restrict__ boxesw,
              float* __restrict__ scw,
              float4* __restrict__ angw, int cap) {
#pragma clang fp contract(off)
    __shared__ int hist[2048];
    __shared__ int csf[256];
    __shared__ unsigned long long sel[1024];
    __shared__ int s_bstar, s_nsel;

    const int b = blockIdx.x;
    const int t = threadIdx.x;
    const int c = min(cnt[b * CNT_STRIDE], cap);
    const unsigned long long* __restrict__ cb = cand + (size_t)b * cap;

    for (int i = t; i < 2048; i += 512) hist[i] = 0;
    sel[t] = 0; sel[t + 512] = 0;
    if (t == 0) { s_nsel = 0; s_bstar = 0; }
    __syncthreads();

    // --- histogram over score mantissa bits (monotonic bucket in [0.7,1)) ---
    for (int i = t; i < c; i += 512) {
        atomicAdd(&hist[(int)((cb[i] >> 44) & 0x7FF)], 1);
    }
    __syncthreads();

    // --- two-level parallel suffix scan to find cut bucket bstar ---
    {
        if (t < 256) {
            int s = 0;
            #pragma unroll
            for (int j = 0; j < 8; ++j) s += hist[t * 8 + j];
            csf[t] = s;
        }
        __syncthreads();
        for (int off = 1; off < 256; off <<= 1) {
            int v2 = 0;
            if (t < 256) v2 = csf[t] + ((t + off < 256) ? csf[t + off] : 0);
            __syncthreads();
            if (t < 256) csf[t] = v2;
            __syncthreads();
        }
        // csf[t] = count of candidates in buckets >= t*8
        if (t < 256) {
            int cs_t  = csf[t];
            int cs_t1 = (t == 255) ? 0 : csf[t + 1];
            if (cs_t >= KTOP && cs_t1 < KTOP) {    // crossing chunk (at most one t)
                int cum = cs_t1, bstar = t * 8;
                for (int j = 7; j >= 0; --j) {
                    cum += hist[t * 8 + j];
                    if (cum >= KTOP) { bstar = t * 8 + j; break; }
                }
                s_bstar = bstar;
            }
        }
        __syncthreads();
    }

    // --- compact candidates in buckets >= bstar (~520 expected) ---
    const int bstar = s_bstar;
    for (int i = t; i < c; i += 512) {
        unsigned long long k = cb[i];
        if ((int)((k >> 44) & 0x7FF) >= bstar) {
            int p = atomicAdd(&s_nsel, 1);
            if (p < 1024) sel[p] = k;
        }
    }
    __syncthreads();
    const int v = min(s_nsel, KTOP);

    // --- bitonic sort, 1024 keys, descending (key = score_bits<<32 | ~idx) ---
    for (int k = 2; k <= 1024; k <<= 1) {
        for (int j = k >> 1; j > 0; j >>= 1) {
            __syncthreads();
            int i0 = ((t & ~(j - 1)) << 1) | (t & (j - 1));
            int i1 = i0 | j;
            unsigned long long a = sel[i0], bb = sel[i1];
            bool up = ((i0 & k) == 0);          // up: larger key first
            if ((a < bb) == up) { sel[i0] = bb; sel[i1] = a; }
        }
    }
    __syncthreads();

    // --- gather top-512 rows, xywh -> xyxy, stash boxes/scores/angles ---
    {
        int s = t;
        float4 bx = make_float4(0.f, 0.f, 0.f, 0.f);
        float4 an = make_float4(0.f, 0.f, 0.f, 0.f);
        float scv = 0.f;
        if (s < v) {
            unsigned long long k = sel[s];
            scv = __uint_as_float((unsigned int)(k >> 32));
            int gid = (int)(~(unsigned int)(k & 0xFFFFFFFFull));
            const float* row = pred + ((size_t)b * N_ANCH + gid) * 9;
            float cx = row[0], cy = row[1], w = row[2], h = row[3];
            float hw = w * 0.5f, hh = h * 0.5f;   // exact halving
            bx = make_float4(cx - hw, cy - hh, cx + hw, cy + hh);
            an = make_float4(row[6], row[7], row[8], 0.f);
        }
        boxesw[(size_t)b * KTOP + s] = bx;
        scw[(size_t)b * KTOP + s] = scv;
        angw[(size_t)b * KTOP + s] = an;
        if (t == 0) cnt[b * CNT_STRIDE + 1] = v;
    }
}

// ---------------------------------------------------------------------------
// K2b: IoU bitmask, whole-chip parallel. Block (w, b) computes mask word w for
// all 512 rows of image b: msk[b][w][i] bit jj set iff IoU(i, w*64+jj) > 0.45
// with j > i. grid = (8, B) = 512 blocks, block = 256.
// ---------------------------------------------------------------------------
__global__ void __launch_bounds__(256)
iou_kernel(const float4* __restrict__ boxesw,
           unsigned long long* __restrict__ mskw) {
#pragma clang fp contract(off)
    __shared__ float4 bxs[KTOP];

    const int w = blockIdx.x;
    const int b = blockIdx.y;
    const int t = threadIdx.x;

    bxs[t]       = boxesw[(size_t)b * KTOP + t];
    bxs[t + 256] = boxesw[(size_t)b * KTOP + t + 256];
    __syncthreads();

    const int j0 = w << 6;
    #pragma unroll
    for (int rep = 0; rep < 2; ++rep) {
        const int i = t + (rep << 8);
        float4 bi = bxs[i];
        float ai = (bi.z - bi.x) * (bi.w - bi.y);
        unsigned long long mword = 0;
        if (j0 + 63 > i) {          // strip has at least one j > i
            #pragma unroll 8
            for (int jj = 0; jj < 64; ++jj) {
                float4 bj = bxs[j0 + jj];        // broadcast across lanes
                float xx1 = fmaxf(bi.x, bj.x);
                float yy1 = fmaxf(bi.y, bj.y);
                float xx2 = fminf(bi.z, bj.z);
                float yy2 = fminf(bi.w, bj.w);
                float ww = fmaxf(xx2 - xx1, 0.f);
                float hh = fmaxf(yy2 - yy1, 0.f);
                float inter = ww * hh;
                float aj = (bj.z - bj.x) * (bj.w - bj.y);
                float uni = ai + aj - inter;
                float iou = inter / (uni + 1e-7f);
                mword |= (unsigned long long)(iou > 0.45f) << jj;
            }
            if (j0 <= i) mword &= (~0ull) << (i - j0 + 1);  // keep only j > i
        }
        mskw[(((size_t)b << 3) + w) * KTOP + i] = mword;    // coalesced
    }
}

// ---------------------------------------------------------------------------
// K2c: greedy suppression + output. grid = B, block = 512. Masks staged to
// LDS (padded stride 516 -> conflict-free broadcast reads). Suppression runs
// wave-redundantly: every lane of wave 0 keeps all 8 rm words in registers
// and does 8 broadcast LDS reads per kept box (no single-lane serial chain).
// ---------------------------------------------------------------------------
__global__ void __launch_bounds__(512)
suppress_kernel(const float4* __restrict__ boxesw,
                const float* __restrict__ scw,
                const float4* __restrict__ angw,
                const unsigned long long* __restrict__ mskw,
                const int* __restrict__ cnt,
                float* __restrict__ out) {
    __shared__ unsigned long long mlds[8 * 516];
    __shared__ unsigned long long rmw_s[8];

    const int b = blockIdx.x;
    const int t = threadIdx.x;
    const int v = cnt[b * CNT_STRIDE + 1];

    #pragma unroll
    for (int w = 0; w < 8; ++w)
        mlds[w * 516 + t] = mskw[(((size_t)b << 3) + w) * KTOP + t];
    __syncthreads();

    if (t < 64) {
        unsigned long long rm[8] = {0, 0, 0, 0, 0, 0, 0, 0};
        for (int w = 0; w < 8 && (w << 6) < v; ++w) {
            int rem = v - (w << 6);
            unsigned long long valid = (rem >= 64) ? ~0ull : ((1ull << rem) - 1ull);
            unsigned long long alive = ~rm[w] & valid;
            while (alive) {
                int bit = __ffsll(alive) - 1;
                int i = (w << 6) + bit;
                #pragma unroll
                for (int u = 0; u < 8; ++u) rm[u] |= mlds[u * 516 + i];
                alive = ~rm[w] & valid;
                alive &= (bit == 63) ? 0ull : (~0ull << (bit + 1));
            }
        }
        if (t < 8) rmw_s[t] = rm[t];
    }
    __syncthreads();

    // --- output: [x1,y1,x2,y2,conf,0,pitch,yaw,roll] or zeros ---
    {
        int s = t;
        float scv = scw[(size_t)b * KTOP + s];
        bool keep = (scv > 0.7f) && !((rmw_s[s >> 6] >> (s & 63)) & 1ull);
        float* o = out + ((size_t)b * KTOP + s) * 9;
        if (keep) {
            float4 bx = boxesw[(size_t)b * KTOP + s];
            float4 an = angw[(size_t)b * KTOP + s];
            o[0] = bx.x; o[1] = bx.y; o[2] = bx.z; o[3] = bx.w;
            o[4] = scv;  o[5] = 0.f;
            o[6] = an.x; o[7] = an.y; o[8] = an.z;
        } else {
            o[0] = 0.f; o[1] = 0.f; o[2] = 0.f; o[3] = 0.f;
            o[4] = 0.f; o[5] = 0.f; o[6] = 0.f; o[7] = 0.f; o[8] = 0.f;
        }
    }
}

// ---------------------------------------------------------------------------
extern "C" void kernel_launch(void* const* d_in, const int* in_sizes, int n_in,
                              void* d_out, int out_size, void* d_ws, size_t ws_size,
                              hipStream_t stream) {
    const float* pred = (const float*)d_in[0];
    float* out = (float*)d_out;
    char* ws = (char*)d_ws;

    // workspace layout (all 16B-aligned offsets):
    //   cnt    : 64 counters, 256B stride                      (16 KB)
    //   boxesw : [B][512] float4                               (512 KB)
    //   scw    : [B][512] float                                (128 KB)
    //   angw   : [B][512] float4                               (512 KB)
    //   mskw   : [B][8][512] u64                               (2 MB)
    //   cand   : [B][cap] u64                                  (cap*512 B)
    int* cnt = (int*)ws;
    size_t off = (size_t)BATCH * CNT_STRIDE * 4;
    float4* boxesw = (float4*)(ws + off); off += (size_t)BATCH * KTOP * sizeof(float4);
    float*  scw    = (float*)(ws + off);  off += (size_t)BATCH * KTOP * sizeof(float);
    float4* angw   = (float4*)(ws + off); off += (size_t)BATCH * KTOP * sizeof(float4);
    unsigned long long* mskw = (unsigned long long*)(ws + off);
    off += (size_t)BATCH * 8 * KTOP * sizeof(unsigned long long);
    unsigned long long* cand = (unsigned long long*)(ws + off);

    int cap = 8192;   // mean candidates/image ~5073, sigma ~69 -> huge headroom
    size_t need = off + (size_t)BATCH * cap * sizeof(unsigned long long);
    if (ws_size < need) {
        cap = (int)((ws_size > off ? (ws_size - off) : 0) /
                    (BATCH * sizeof(unsigned long long)));
    }

    zero_cnt_kernel<<<1, 64, 0, stream>>>(cnt);

    dim3 g1((N_ANCH + 255) / 256, BATCH);
    filter_kernel<<<g1, 256, 0, stream>>>(pred, cand, cnt, cap);

    select_kernel<<<BATCH, 512, 0, stream>>>(pred, cand, cnt, boxesw, scw, angw, cap);

    iou_kernel<<<dim3(8, BATCH), 256, 0, stream>>>(boxesw, mskw);

    suppress_kernel<<<BATCH, 512, 0, stream>>>(boxesw, scw, angw, mskw, cnt, out);
}